// Round 3
// baseline (547.129 us; speedup 1.0000x reference)
//
#include <hip/hip_runtime.h>

// ---------------------------------------------------------------------------
// TextGCN (2-layer GCN, eval mode) on MI355X.
// Fusions:
//   * xw1_word = word @ (W_lin@W1) + (b_lin@W1)   -- never materialize [N,768] x
//   * layer 2: agg(h1@W2)[mask] == agg(h1)[mask] @ W2  -- aggregate-then-project
// CSR-by-destination built once per call, entries hold RAW weights (src, w);
// symmetric normalization dis[src]*w*dis[dst] is applied on the fly in the
// aggregation kernels (dis[dst] factors out of the row sum). This removes all
// deg atomics; self-loops get reserved slot offs[i] (no atomic either).
// ---------------------------------------------------------------------------

// cnt histogram over edge destinations (self loops NOT counted; scan adds +1)
__global__ void k_cnt(const int* __restrict__ ei, int E, int* __restrict__ cnt) {
  int e = blockIdx.x * blockDim.x + threadIdx.x;
  if (e < E) atomicAdd(cnt + ei[E + e], 1);
}

// ---- 3-kernel exclusive scan of (cnt[i]+1) -> offs[N+1]; also writes the
// self-loop entry at offs[i] and cursor[i]=offs[i]+1 ----
__global__ void k_scan_reduce(const int* __restrict__ cnt, int N, int* __restrict__ bsum) {
  __shared__ int sd[256];
  int b = blockIdx.x, t = threadIdx.x;
  int base = b * 1024 + t * 4;
  int s = 0;
#pragma unroll
  for (int j = 0; j < 4; ++j) s += (base + j < N) ? cnt[base + j] + 1 : 0;
  sd[t] = s; __syncthreads();
  for (int off = 128; off > 0; off >>= 1) {
    if (t < off) sd[t] += sd[t + off];
    __syncthreads();
  }
  if (t == 0) bsum[b] = sd[0];
}

__global__ void k_scan_small(int* __restrict__ bsum, int nb) {
  __shared__ int s[128];
  int t = threadIdx.x;
  int v = (t < nb) ? bsum[t] : 0;
  s[t] = v; __syncthreads();
  for (int off = 1; off < 128; off <<= 1) {
    int x = (t >= off) ? s[t - off] : 0;
    __syncthreads();
    s[t] += x;
    __syncthreads();
  }
  if (t < nb) bsum[t] = s[t] - v;   // exclusive
}

__global__ void k_scan_final(const int* __restrict__ cnt, int N, const int* __restrict__ bsum,
                             int* __restrict__ offs, int* __restrict__ cursor,
                             int2* __restrict__ entries) {
  __shared__ int sd[256];
  int b = blockIdx.x, t = threadIdx.x;
  int base = b * 1024 + t * 4;
  int v[4], loc = 0;
#pragma unroll
  for (int j = 0; j < 4; ++j) { v[j] = (base + j < N) ? cnt[base + j] + 1 : 0; loc += v[j]; }
  sd[t] = loc; __syncthreads();
  for (int off = 1; off < 256; off <<= 1) {
    int x = (t >= off) ? sd[t - off] : 0;
    __syncthreads();
    sd[t] += x;
    __syncthreads();
  }
  int run = bsum[b] + sd[t] - loc;  // exclusive prefix for this thread's 4 elems
#pragma unroll
  for (int j = 0; j < 4; ++j) {
    if (base + j < N) {
      int i = base + j;
      offs[i] = run;
      cursor[i] = run + 1;                              // slot 0 = self loop
      entries[run] = make_int2(i, __float_as_int(1.0f)); // self loop, raw w=1
      run += v[j];
    }
  }
  if (b == gridDim.x - 1 && t == 255) offs[N] = run;  // total = N + E
}

// fill CSR entries with RAW weights: (src, w), bucketed by destination
__global__ void k_fill(const int* __restrict__ ei, const float* __restrict__ ew,
                       int E, int* __restrict__ cursor, int2* __restrict__ entries) {
  int e = blockIdx.x * blockDim.x + threadIdx.x;
  if (e >= E) return;
  int r = ei[e], c = ei[E + e];
  int pos = atomicAdd(cursor + c, 1);
  entries[pos] = make_int2(r, __float_as_int(ew[e]));
}

// segmented sum of raw weights per row -> dis = rsqrt(deg). Atomic-free.
__global__ void k_degdis(const int2* __restrict__ entries, const int* __restrict__ offs,
                         float* __restrict__ dis, int N) {
  int i = blockIdx.x * blockDim.x + threadIdx.x;
  if (i >= N) return;
  int p = offs[i], pe = offs[i + 1];
  float d = 0.f;
  for (; p < pe; ++p) d += __int_as_float(entries[p].y);
  dis[i] = d > 0.f ? rsqrtf(fmaxf(d, 1e-12f)) : 0.f;
}

// ---------------------------------------------------------------------------
// Tiled SGEMM: out[R,64] = X[R,K] @ W[K,64] (+bias). 64x64 tile, BK=32.
// 256 threads; thread (tx,ty) computes 4x4 micro-tile. Xs transposed, stride 68.
// ---------------------------------------------------------------------------
template <bool HAS_BIAS>
__global__ __launch_bounds__(256)
void k_gemm64(const float* __restrict__ X, const float* __restrict__ W,
              const float* __restrict__ bias, float* __restrict__ out,
              int R, int K) {
  __shared__ float Xs[32][68];
  __shared__ float Ws[32][64];
  const int t = threadIdx.x;
  const int row0 = blockIdx.x * 64;
  const int tx = t & 15;
  const int ty = t >> 4;
  const int xr = t >> 3;
  const int xk = (t & 7) << 2;
  const int wc = (t & 15) << 2;
  const int wk = t >> 4;
  float acc[4][4] = {};

  for (int k0 = 0; k0 < K; k0 += 32) {
#pragma unroll
    for (int h = 0; h < 2; ++h) {
      int r = xr + h * 32;
      int gr = row0 + r;
      int gk = k0 + xk;
      float4 v = make_float4(0.f, 0.f, 0.f, 0.f);
      if (gr < R && gk < K) v = *(const float4*)(X + (size_t)gr * K + gk);
      Xs[xk + 0][r] = v.x;
      Xs[xk + 1][r] = v.y;
      Xs[xk + 2][r] = v.z;
      Xs[xk + 3][r] = v.w;
    }
#pragma unroll
    for (int h = 0; h < 2; ++h) {
      int kk = wk + h * 16;
      int gk = k0 + kk;
      float4 v = make_float4(0.f, 0.f, 0.f, 0.f);
      if (gk < K) v = *(const float4*)(W + (size_t)gk * 64 + wc);
      *(float4*)&Ws[kk][wc] = v;
    }
    __syncthreads();
#pragma unroll
    for (int kk = 0; kk < 32; ++kk) {
      float4 xa = *(const float4*)&Xs[kk][ty * 4];
      float4 wb = *(const float4*)&Ws[kk][tx * 4];
      acc[0][0] = fmaf(xa.x, wb.x, acc[0][0]);
      acc[0][1] = fmaf(xa.x, wb.y, acc[0][1]);
      acc[0][2] = fmaf(xa.x, wb.z, acc[0][2]);
      acc[0][3] = fmaf(xa.x, wb.w, acc[0][3]);
      acc[1][0] = fmaf(xa.y, wb.x, acc[1][0]);
      acc[1][1] = fmaf(xa.y, wb.y, acc[1][1]);
      acc[1][2] = fmaf(xa.y, wb.z, acc[1][2]);
      acc[1][3] = fmaf(xa.y, wb.w, acc[1][3]);
      acc[2][0] = fmaf(xa.z, wb.x, acc[2][0]);
      acc[2][1] = fmaf(xa.z, wb.y, acc[2][1]);
      acc[2][2] = fmaf(xa.z, wb.z, acc[2][2]);
      acc[2][3] = fmaf(xa.z, wb.w, acc[2][3]);
      acc[3][0] = fmaf(xa.w, wb.x, acc[3][0]);
      acc[3][1] = fmaf(xa.w, wb.y, acc[3][1]);
      acc[3][2] = fmaf(xa.w, wb.z, acc[3][2]);
      acc[3][3] = fmaf(xa.w, wb.w, acc[3][3]);
    }
    __syncthreads();
  }

  float b0 = 0.f, b1 = 0.f, b2 = 0.f, b3 = 0.f;
  if (HAS_BIAS) {
    b0 = bias[tx * 4 + 0]; b1 = bias[tx * 4 + 1];
    b2 = bias[tx * 4 + 2]; b3 = bias[tx * 4 + 3];
  }
#pragma unroll
  for (int i = 0; i < 4; ++i) {
    int gr = row0 + ty * 4 + i;
    if (gr < R) {
      float4 o;
      o.x = acc[i][0] + b0;
      o.y = acc[i][1] + b1;
      o.z = acc[i][2] + b2;
      o.w = acc[i][3] + b3;
      *(float4*)(out + (size_t)gr * 64 + tx * 4) = o;
    }
  }
}

// layer-1 aggregation: out[i] = relu(bias + dis[i] * sum (w*dis[src]) * x[src])
__global__ void k_agg(const float* __restrict__ xin, const int2* __restrict__ entries,
                      const int* __restrict__ offs, const float* __restrict__ dis,
                      const float* __restrict__ bias, float* __restrict__ xout, int N) {
  const int lane = threadIdx.x & 63;
  const int wv = threadIdx.x >> 6;
  int i = blockIdx.x * 4 + wv;
  if (i >= N) return;
  int p = offs[i], pe = offs[i + 1];
  float acc = 0.f;
  for (; p + 4 <= pe; p += 4) {
    int2 e0 = entries[p + 0];
    int2 e1 = entries[p + 1];
    int2 e2 = entries[p + 2];
    int2 e3 = entries[p + 3];
    float w0 = __int_as_float(e0.y) * dis[e0.x];
    float w1 = __int_as_float(e1.y) * dis[e1.x];
    float w2 = __int_as_float(e2.y) * dis[e2.x];
    float w3 = __int_as_float(e3.y) * dis[e3.x];
    float x0 = xin[(size_t)e0.x * 64 + lane];
    float x1 = xin[(size_t)e1.x * 64 + lane];
    float x2 = xin[(size_t)e2.x * 64 + lane];
    float x3 = xin[(size_t)e3.x * 64 + lane];
    acc = fmaf(x0, w0, acc);
    acc = fmaf(x1, w1, acc);
    acc = fmaf(x2, w2, acc);
    acc = fmaf(x3, w3, acc);
  }
  for (; p < pe; ++p) {
    int2 e = entries[p];
    acc = fmaf(xin[(size_t)e.x * 64 + lane], __int_as_float(e.y) * dis[e.x], acc);
  }
  acc = fmaf(acc, dis[i], bias[lane]);
  acc = fmaxf(acc, 0.f);
  xout[(size_t)i * 64 + lane] = acc;
}

// masked layer-2 aggregation (no bias/relu; GEMM adds b2) + emit y[mask]
__global__ void k_agg2m(const float* __restrict__ xin, const int2* __restrict__ entries,
                        const int* __restrict__ offs, const float* __restrict__ dis,
                        const int* __restrict__ mask, const int* __restrict__ y,
                        float* __restrict__ tout, float* __restrict__ outY, int M) {
  const int lane = threadIdx.x & 63;
  const int wv = threadIdx.x >> 6;
  int o = blockIdx.x * 4 + wv;
  if (o >= M) return;
  int i = mask[o];
  int p = offs[i], pe = offs[i + 1];
  float acc = 0.f;
  for (; p + 4 <= pe; p += 4) {
    int2 e0 = entries[p + 0];
    int2 e1 = entries[p + 1];
    int2 e2 = entries[p + 2];
    int2 e3 = entries[p + 3];
    float w0 = __int_as_float(e0.y) * dis[e0.x];
    float w1 = __int_as_float(e1.y) * dis[e1.x];
    float w2 = __int_as_float(e2.y) * dis[e2.x];
    float w3 = __int_as_float(e3.y) * dis[e3.x];
    float x0 = xin[(size_t)e0.x * 64 + lane];
    float x1 = xin[(size_t)e1.x * 64 + lane];
    float x2 = xin[(size_t)e2.x * 64 + lane];
    float x3 = xin[(size_t)e3.x * 64 + lane];
    acc = fmaf(x0, w0, acc);
    acc = fmaf(x1, w1, acc);
    acc = fmaf(x2, w2, acc);
    acc = fmaf(x3, w3, acc);
  }
  for (; p < pe; ++p) {
    int2 e = entries[p];
    acc = fmaf(xin[(size_t)e.x * 64 + lane], __int_as_float(e.y) * dis[e.x], acc);
  }
  tout[(size_t)o * 64 + lane] = acc * dis[i];
  if (lane == 0) outY[o] = (float)y[i];
}

extern "C" void kernel_launch(void* const* d_in, const int* in_sizes, int n_in,
                              void* d_out, int out_size, void* d_ws, size_t ws_size,
                              hipStream_t stream) {
  const float* doc   = (const float*)d_in[0];
  const float* wordf = (const float*)d_in[1];
  const float* ew    = (const float*)d_in[2];
  const float* Wlin  = (const float*)d_in[3];
  const float* blin  = (const float*)d_in[4];
  const float* W1    = (const float*)d_in[5];
  const float* b1    = (const float*)d_in[6];
  const float* W2    = (const float*)d_in[7];
  const float* b2    = (const float*)d_in[8];
  const int*   ei    = (const int*)d_in[9];
  const int*   mask  = (const int*)d_in[10];
  const int*   y     = (const int*)d_in[11];

  const int E  = in_sizes[2];
  const int M  = in_sizes[10];
  const int ND = in_sizes[0] / 768;
  const int NW = in_sizes[1] / 300;
  const int N  = ND + NW;
  const int NE = N + E;

  // workspace carve (aligned 256B)
  char* p = (char*)d_ws;
  auto carve = [&](size_t bytes) -> void* {
    void* q = (void*)p;
    p += (bytes + 255) & ~(size_t)255;
    return q;
  };
  float* XlinB  = (float*)carve(301 * 768 * 4);   // [Wlin ; blin]
  float* WfuseB = (float*)carve(301 * 64 * 4);    // rows 0..299 Wfuse, row 300 bfuse
  float* dis    = (float*)carve((size_t)N * 4);
  int*   cnt    = (int*)carve((size_t)N * 4);
  int*   offs   = (int*)carve(((size_t)N + 1) * 4);
  int*   cursor = (int*)carve((size_t)N * 4);
  int*   bsum   = (int*)carve(1024);
  int2*  entries = (int2*)carve((size_t)NE * 8);
  float* xw1    = (float*)carve((size_t)N * 64 * 4);
  float* h1     = (float*)carve((size_t)N * 64 * 4);
  float* tmask  = xw1;  // xw1 dead after k_agg; reuse for masked agg output

  hipMemsetAsync(cnt, 0, (size_t)N * 4, stream);
  hipMemcpyAsync(XlinB, Wlin, (size_t)300 * 768 * 4, hipMemcpyDeviceToDevice, stream);
  hipMemcpyAsync(XlinB + (size_t)300 * 768, blin, 768 * 4, hipMemcpyDeviceToDevice, stream);

  // fused weight: [Wlin;blin] @ W1  -> [301,64]
  k_gemm64<false><<<(301 + 63) / 64, 256, 0, stream>>>(XlinB, W1, nullptr, WfuseB, 301, 768);

  // CSR build (raw weights)
  k_cnt<<<(E + 255) / 256, 256, 0, stream>>>(ei, E, cnt);
  int nb = (N + 1023) / 1024;
  k_scan_reduce<<<nb, 256, 0, stream>>>(cnt, N, bsum);
  k_scan_small<<<1, 128, 0, stream>>>(bsum, nb);
  k_scan_final<<<nb, 256, 0, stream>>>(cnt, N, bsum, offs, cursor, entries);
  k_fill<<<(E + 255) / 256, 256, 0, stream>>>(ei, ew, E, cursor, entries);
  k_degdis<<<(N + 255) / 256, 256, 0, stream>>>(entries, offs, dis, N);

  // layer-1 projection: doc rows use W1 (K=768); word rows use fused W (K=300)
  k_gemm64<false><<<(ND + 63) / 64, 256, 0, stream>>>(doc, W1, nullptr, xw1, ND, 768);
  k_gemm64<true><<<(NW + 63) / 64, 256, 0, stream>>>(wordf, WfuseB, WfuseB + (size_t)300 * 64,
                                                     xw1 + (size_t)ND * 64, NW, 300);

  // layer-1 aggregation (+b1, relu), norm applied on the fly
  k_agg<<<(N + 3) / 4, 256, 0, stream>>>(xw1, entries, offs, dis, b1, h1, N);

  // layer-2: aggregate masked nodes over h1, then project [M,64]@[64,64]+b2
  float* out0 = (float*)d_out;
  float* outY = out0 + (size_t)M * 64;
  k_agg2m<<<(M + 3) / 4, 256, 0, stream>>>(h1, entries, offs, dis, mask, y, tmask, outY, M);
  k_gemm64<true><<<(M + 63) / 64, 256, 0, stream>>>(tmask, W2, b2, out0, M, 64);
}

// Round 4
// 501.675 us; speedup vs baseline: 1.0906x; 1.0906x over previous
//
#include <hip/hip_runtime.h>

// ---------------------------------------------------------------------------
// TextGCN (2-layer GCN, eval mode) on MI355X.
// Fusions:
//   * xw1_word = word @ (W_lin@W1) + (b_lin@W1)  (never materialize [N,768] x)
//   * layer 2: agg(h1@W2)[mask] == agg(h1)[mask] @ W2
// CSR holds RAW weights; symmetric norm applied on the fly (dis[dst] factors
// out of the row sum). Self-loop gets reserved slot offs[i] (no atomic).
// Wide phase dispatches co-schedule independent work:
//   phase1 = fuseGEMM || cnt ; phase2 = fill || docGEMM(split-K 4) || wordGEMM
//   phase3 = degdis || partial-reduce.  Doc partials alias the h1 region.
// ---------------------------------------------------------------------------

// ---- shared tiled-SGEMM body: out[R,64] = X[R,K(ldx)] @ W[K,64] (+bias),
// K-range [k0b,k0e); 64x64 tile, BK=32, 256 thr, 4x4 micro-tile.
// LAST: row R-1 is read from lastRow pointer (virtual concat row).
template <bool LAST>
__device__ __forceinline__ void gemm_tile_body(
    const float* __restrict__ X, int ldx, const float* __restrict__ lastRow,
    const float* __restrict__ W, const float* __restrict__ bias,
    float* __restrict__ out, int R, int K, int k0b, int k0e, int row0) {
  __shared__ float Xs[32][68];
  __shared__ float Ws[32][64];
  const int t = threadIdx.x;
  const int tx = t & 15;
  const int ty = t >> 4;
  const int xr = t >> 3;
  const int xk = (t & 7) << 2;
  const int wc = (t & 15) << 2;
  const int wk = t >> 4;
  float acc[4][4] = {};

  for (int k0 = k0b; k0 < k0e; k0 += 32) {
#pragma unroll
    for (int h = 0; h < 2; ++h) {
      int r = xr + h * 32;
      int gr = row0 + r;
      int gk = k0 + xk;
      float4 v = make_float4(0.f, 0.f, 0.f, 0.f);
      if (gr < R && gk < K) {
        const float* xp = (LAST && gr == R - 1) ? lastRow : X + (size_t)gr * ldx;
        v = *(const float4*)(xp + gk);
      }
      Xs[xk + 0][r] = v.x;
      Xs[xk + 1][r] = v.y;
      Xs[xk + 2][r] = v.z;
      Xs[xk + 3][r] = v.w;
    }
#pragma unroll
    for (int h = 0; h < 2; ++h) {
      int kk = wk + h * 16;
      int gk = k0 + kk;
      float4 v = make_float4(0.f, 0.f, 0.f, 0.f);
      if (gk < K) v = *(const float4*)(W + (size_t)gk * 64 + wc);
      *(float4*)&Ws[kk][wc] = v;
    }
    __syncthreads();
#pragma unroll
    for (int kk = 0; kk < 32; ++kk) {
      float4 xa = *(const float4*)&Xs[kk][ty * 4];
      float4 wb = *(const float4*)&Ws[kk][tx * 4];
      acc[0][0] = fmaf(xa.x, wb.x, acc[0][0]);
      acc[0][1] = fmaf(xa.x, wb.y, acc[0][1]);
      acc[0][2] = fmaf(xa.x, wb.z, acc[0][2]);
      acc[0][3] = fmaf(xa.x, wb.w, acc[0][3]);
      acc[1][0] = fmaf(xa.y, wb.x, acc[1][0]);
      acc[1][1] = fmaf(xa.y, wb.y, acc[1][1]);
      acc[1][2] = fmaf(xa.y, wb.z, acc[1][2]);
      acc[1][3] = fmaf(xa.y, wb.w, acc[1][3]);
      acc[2][0] = fmaf(xa.z, wb.x, acc[2][0]);
      acc[2][1] = fmaf(xa.z, wb.y, acc[2][1]);
      acc[2][2] = fmaf(xa.z, wb.z, acc[2][2]);
      acc[2][3] = fmaf(xa.z, wb.w, acc[2][3]);
      acc[3][0] = fmaf(xa.w, wb.x, acc[3][0]);
      acc[3][1] = fmaf(xa.w, wb.y, acc[3][1]);
      acc[3][2] = fmaf(xa.w, wb.z, acc[3][2]);
      acc[3][3] = fmaf(xa.w, wb.w, acc[3][3]);
    }
    __syncthreads();
  }

  float b0 = 0.f, b1 = 0.f, b2 = 0.f, b3 = 0.f;
  if (bias) {
    b0 = bias[tx * 4 + 0]; b1 = bias[tx * 4 + 1];
    b2 = bias[tx * 4 + 2]; b3 = bias[tx * 4 + 3];
  }
#pragma unroll
  for (int i = 0; i < 4; ++i) {
    int gr = row0 + ty * 4 + i;
    if (gr < R) {
      float4 o;
      o.x = acc[i][0] + b0;
      o.y = acc[i][1] + b1;
      o.z = acc[i][2] + b2;
      o.w = acc[i][3] + b3;
      *(float4*)(out + (size_t)gr * 64 + tx * 4) = o;
    }
  }
}

// phase1: blocks [0,gemmTiles) fuse GEMM [Wlin;blin]@W1 -> WfuseB[301,64];
//         blocks [gemmTiles,..) cnt histogram over edge destinations.
__global__ __launch_bounds__(256) void k_phase1(
    const float* __restrict__ Wlin, const float* __restrict__ blin,
    const float* __restrict__ W1, float* __restrict__ WfuseB,
    const int* __restrict__ ei, int E, int* __restrict__ cnt, int gemmTiles) {
  int b = blockIdx.x;
  if (b < gemmTiles) {
    gemm_tile_body<true>(Wlin, 768, blin, W1, nullptr, WfuseB, 301, 768, 0, 768, b * 64);
    return;
  }
  int e = (b - gemmTiles) * 256 + threadIdx.x;
  if (e < E) atomicAdd(cnt + ei[E + e], 1);
}

// ---- 3-kernel exclusive scan of (cnt[i]+1) -> offs[N+1]; writes self-loop
// entry at offs[i] and cursor[i]=offs[i]+1 ----
__global__ void k_scan_reduce(const int* __restrict__ cnt, int N, int* __restrict__ bsum) {
  __shared__ int sd[256];
  int b = blockIdx.x, t = threadIdx.x;
  int base = b * 1024 + t * 4;
  int s = 0;
#pragma unroll
  for (int j = 0; j < 4; ++j) s += (base + j < N) ? cnt[base + j] + 1 : 0;
  sd[t] = s; __syncthreads();
  for (int off = 128; off > 0; off >>= 1) {
    if (t < off) sd[t] += sd[t + off];
    __syncthreads();
  }
  if (t == 0) bsum[b] = sd[0];
}

__global__ void k_scan_small(int* __restrict__ bsum, int nb) {
  __shared__ int s[128];
  int t = threadIdx.x;
  int v = (t < nb) ? bsum[t] : 0;
  s[t] = v; __syncthreads();
  for (int off = 1; off < 128; off <<= 1) {
    int x = (t >= off) ? s[t - off] : 0;
    __syncthreads();
    s[t] += x;
    __syncthreads();
  }
  if (t < nb) bsum[t] = s[t] - v;   // exclusive
}

__global__ void k_scan_final(const int* __restrict__ cnt, int N, const int* __restrict__ bsum,
                             int* __restrict__ offs, int* __restrict__ cursor,
                             int2* __restrict__ entries) {
  __shared__ int sd[256];
  int b = blockIdx.x, t = threadIdx.x;
  int base = b * 1024 + t * 4;
  int v[4], loc = 0;
#pragma unroll
  for (int j = 0; j < 4; ++j) { v[j] = (base + j < N) ? cnt[base + j] + 1 : 0; loc += v[j]; }
  sd[t] = loc; __syncthreads();
  for (int off = 1; off < 256; off <<= 1) {
    int x = (t >= off) ? sd[t - off] : 0;
    __syncthreads();
    sd[t] += x;
    __syncthreads();
  }
  int run = bsum[b] + sd[t] - loc;
#pragma unroll
  for (int j = 0; j < 4; ++j) {
    if (base + j < N) {
      int i = base + j;
      offs[i] = run;
      cursor[i] = run + 1;                               // slot 0 = self loop
      entries[run] = make_int2(i, __float_as_int(1.0f)); // raw w=1
      run += v[j];
    }
  }
  if (b == gridDim.x - 1 && t == 255) offs[N] = run;  // total = N + E
}

// phase2: blocks [0,fillBlocks) CSR fill; then doc split-K GEMM tiles; then word GEMM.
__global__ __launch_bounds__(256) void k_phase2(
    const int* __restrict__ ei, const float* __restrict__ ew, int E,
    int* __restrict__ cursor, int2* __restrict__ entries,
    const float* __restrict__ doc, const float* __restrict__ W1,
    float* __restrict__ Pdoc, int ND,
    const float* __restrict__ wordf, const float* __restrict__ WfuseB,
    float* __restrict__ xw1word, int NW,
    int fillBlocks, int docTiles, int nsplit) {
  int b = blockIdx.x;
  if (b < fillBlocks) {
    int e = b * 256 + threadIdx.x;
    if (e < E) {
      int r = ei[e], c = ei[E + e];
      int pos = atomicAdd(cursor + c, 1);
      entries[pos] = make_int2(r, __float_as_int(ew[e]));
    }
    return;
  }
  b -= fillBlocks;
  int docBlocks = docTiles * nsplit;
  if (b < docBlocks) {
    int s = b / docTiles, tile = b % docTiles;
    gemm_tile_body<false>(doc, 768, nullptr, W1, nullptr,
                          Pdoc + (size_t)s * ND * 64, ND, 768,
                          s * 192, s * 192 + 192, tile * 64);
  } else {
    b -= docBlocks;
    gemm_tile_body<false>(wordf, 300, nullptr, WfuseB, WfuseB + (size_t)300 * 64,
                          xw1word, NW, 300, 0, 300, b * 64);
  }
}

// phase3: blocks [0,degBlocks) deg->dis (segmented sum over CSR rows, atomic-free);
//         remaining blocks reduce the 4 doc partials into xw1[0..ND).
__global__ void k_phase3(const int2* __restrict__ entries, const int* __restrict__ offs,
                         float* __restrict__ dis, int N,
                         const float* __restrict__ Pdoc, float* __restrict__ xw1,
                         int ND, int degBlocks) {
  int b = blockIdx.x;
  if (b < degBlocks) {
    int i = b * 256 + threadIdx.x;
    if (i >= N) return;
    int p = offs[i], pe = offs[i + 1];
    float d = 0.f;
    for (; p < pe; ++p) d += __int_as_float(entries[p].y);
    dis[i] = d > 0.f ? rsqrtf(fmaxf(d, 1e-12f)) : 0.f;
    return;
  }
  int i = (b - degBlocks) * 256 + threadIdx.x;   // float4 index
  int n4 = ND * 16;
  if (i >= n4) return;
  const float4* P0 = (const float4*)Pdoc;
  size_t stride = (size_t)ND * 16;
  float4 a = P0[i];
  float4 c1 = P0[i + stride];
  float4 c2 = P0[i + 2 * stride];
  float4 c3 = P0[i + 3 * stride];
  float4 o;
  o.x = a.x + c1.x + c2.x + c3.x;
  o.y = a.y + c1.y + c2.y + c3.y;
  o.z = a.z + c1.z + c2.z + c3.z;
  o.w = a.w + c1.w + c2.w + c3.w;
  ((float4*)xw1)[i] = o;
}

// layer-1 aggregation: out[i] = relu(b1 + dis[i] * sum (w*dis[src]) * x[src])
__global__ void k_agg(const float* __restrict__ xin, const int2* __restrict__ entries,
                      const int* __restrict__ offs, const float* __restrict__ dis,
                      const float* __restrict__ bias, float* __restrict__ xout, int N) {
  const int lane = threadIdx.x & 63;
  const int wv = threadIdx.x >> 6;
  int i = blockIdx.x * 4 + wv;
  if (i >= N) return;
  int p = offs[i], pe = offs[i + 1];
  float acc = 0.f;
  for (; p + 4 <= pe; p += 4) {
    int2 e0 = entries[p + 0];
    int2 e1 = entries[p + 1];
    int2 e2 = entries[p + 2];
    int2 e3 = entries[p + 3];
    float w0 = __int_as_float(e0.y) * dis[e0.x];
    float w1 = __int_as_float(e1.y) * dis[e1.x];
    float w2 = __int_as_float(e2.y) * dis[e2.x];
    float w3 = __int_as_float(e3.y) * dis[e3.x];
    float x0 = xin[(size_t)e0.x * 64 + lane];
    float x1 = xin[(size_t)e1.x * 64 + lane];
    float x2 = xin[(size_t)e2.x * 64 + lane];
    float x3 = xin[(size_t)e3.x * 64 + lane];
    acc = fmaf(x0, w0, acc);
    acc = fmaf(x1, w1, acc);
    acc = fmaf(x2, w2, acc);
    acc = fmaf(x3, w3, acc);
  }
  for (; p < pe; ++p) {
    int2 e = entries[p];
    acc = fmaf(xin[(size_t)e.x * 64 + lane], __int_as_float(e.y) * dis[e.x], acc);
  }
  acc = fmaf(acc, dis[i], bias[lane]);
  acc = fmaxf(acc, 0.f);
  xout[(size_t)i * 64 + lane] = acc;
}

// masked layer-2 aggregation (no bias/relu; GEMM adds b2) + emit y[mask]
__global__ void k_agg2m(const float* __restrict__ xin, const int2* __restrict__ entries,
                        const int* __restrict__ offs, const float* __restrict__ dis,
                        const int* __restrict__ mask, const int* __restrict__ y,
                        float* __restrict__ tout, float* __restrict__ outY, int M) {
  const int lane = threadIdx.x & 63;
  const int wv = threadIdx.x >> 6;
  int o = blockIdx.x * 4 + wv;
  if (o >= M) return;
  int i = mask[o];
  int p = offs[i], pe = offs[i + 1];
  float acc = 0.f;
  for (; p + 4 <= pe; p += 4) {
    int2 e0 = entries[p + 0];
    int2 e1 = entries[p + 1];
    int2 e2 = entries[p + 2];
    int2 e3 = entries[p + 3];
    float w0 = __int_as_float(e0.y) * dis[e0.x];
    float w1 = __int_as_float(e1.y) * dis[e1.x];
    float w2 = __int_as_float(e2.y) * dis[e2.x];
    float w3 = __int_as_float(e3.y) * dis[e3.x];
    float x0 = xin[(size_t)e0.x * 64 + lane];
    float x1 = xin[(size_t)e1.x * 64 + lane];
    float x2 = xin[(size_t)e2.x * 64 + lane];
    float x3 = xin[(size_t)e3.x * 64 + lane];
    acc = fmaf(x0, w0, acc);
    acc = fmaf(x1, w1, acc);
    acc = fmaf(x2, w2, acc);
    acc = fmaf(x3, w3, acc);
  }
  for (; p < pe; ++p) {
    int2 e = entries[p];
    acc = fmaf(xin[(size_t)e.x * 64 + lane], __int_as_float(e.y) * dis[e.x], acc);
  }
  tout[(size_t)o * 64 + lane] = acc * dis[i];
  if (lane == 0) outY[o] = (float)y[i];
}

// plain GEMM wrapper for the final [M,64]@[64,64]+b2
__global__ __launch_bounds__(256) void k_gemm(const float* __restrict__ X, int ldx,
                                              const float* __restrict__ W,
                                              const float* __restrict__ bias,
                                              float* __restrict__ out, int R, int K) {
  gemm_tile_body<false>(X, ldx, nullptr, W, bias, out, R, K, 0, K, blockIdx.x * 64);
}

extern "C" void kernel_launch(void* const* d_in, const int* in_sizes, int n_in,
                              void* d_out, int out_size, void* d_ws, size_t ws_size,
                              hipStream_t stream) {
  const float* doc   = (const float*)d_in[0];
  const float* wordf = (const float*)d_in[1];
  const float* ew    = (const float*)d_in[2];
  const float* Wlin  = (const float*)d_in[3];
  const float* blin  = (const float*)d_in[4];
  const float* W1    = (const float*)d_in[5];
  const float* b1    = (const float*)d_in[6];
  const float* W2    = (const float*)d_in[7];
  const float* b2    = (const float*)d_in[8];
  const int*   ei    = (const int*)d_in[9];
  const int*   mask  = (const int*)d_in[10];
  const int*   y     = (const int*)d_in[11];

  const int E  = in_sizes[2];
  const int M  = in_sizes[10];
  const int ND = in_sizes[0] / 768;
  const int NW = in_sizes[1] / 300;
  const int N  = ND + NW;
  const int NE = N + E;
  const int NSPLIT = 4;

  // workspace carve (aligned 256B)
  char* p = (char*)d_ws;
  auto carve = [&](size_t bytes) -> void* {
    void* q = (void*)p;
    p += (bytes + 255) & ~(size_t)255;
    return q;
  };
  float* WfuseB = (float*)carve(301 * 64 * 4);    // rows 0..299 Wfuse, row 300 bfuse
  float* dis    = (float*)carve((size_t)N * 4);
  int*   cnt    = (int*)carve((size_t)N * 4);
  int*   offs   = (int*)carve(((size_t)N + 1) * 4);
  int*   cursor = (int*)carve((size_t)N * 4);
  int*   bsum   = (int*)carve(1024);
  int2*  entries = (int2*)carve((size_t)NE * 8);
  float* xw1    = (float*)carve((size_t)N * 64 * 4);
  float* h1     = (float*)carve((size_t)N * 64 * 4);  // also holds doc partials
  float* Pdoc   = h1;    // 4*ND*64*4 = 20.5MB <= 25.6MB; dead before k_agg writes h1
  float* tmask  = xw1;   // xw1 dead after k_agg

  hipMemsetAsync(cnt, 0, (size_t)N * 4, stream);

  // phase1: fuse GEMM (5 tiles) || cnt histogram
  const int fuseTiles = (301 + 63) / 64;
  const int cntBlocks = (E + 255) / 256;
  k_phase1<<<fuseTiles + cntBlocks, 256, 0, stream>>>(Wlin, blin, W1, WfuseB, ei, E, cnt, fuseTiles);

  int nb = (N + 1023) / 1024;
  k_scan_reduce<<<nb, 256, 0, stream>>>(cnt, N, bsum);
  k_scan_small<<<1, 128, 0, stream>>>(bsum, nb);
  k_scan_final<<<nb, 256, 0, stream>>>(cnt, N, bsum, offs, cursor, entries);

  // phase2: CSR fill || doc GEMM (split-K 4 -> partials) || word GEMM
  const int fillBlocks = (E + 255) / 256;
  const int docTiles   = (ND + 63) / 64;
  const int wordTiles  = (NW + 63) / 64;
  k_phase2<<<fillBlocks + docTiles * NSPLIT + wordTiles, 256, 0, stream>>>(
      ei, ew, E, cursor, entries,
      doc, W1, Pdoc, ND,
      wordf, WfuseB, xw1 + (size_t)ND * 64, NW,
      fillBlocks, docTiles, NSPLIT);

  // phase3: degdis || partial-reduce into xw1[0..ND)
  const int degBlocks = (N + 255) / 256;
  const int redBlocks = (ND * 16 + 255) / 256;
  k_phase3<<<degBlocks + redBlocks, 256, 0, stream>>>(entries, offs, dis, N,
                                                      Pdoc, xw1, ND, degBlocks);

  // layer-1 aggregation (+b1, relu)
  k_agg<<<(N + 3) / 4, 256, 0, stream>>>(xw1, entries, offs, dis, b1, h1, N);

  // layer-2: masked aggregation over h1, then project [M,64]@[64,64]+b2
  float* out0 = (float*)d_out;
  float* outY = out0 + (size_t)M * 64;
  k_agg2m<<<(M + 3) / 4, 256, 0, stream>>>(h1, entries, offs, dis, mask, y, tmask, outY, M);
  k_gemm<<<(M + 63) / 64, 256, 0, stream>>>(tmask, 64, W2, b2, out0, M, 64);
}

// Round 5
// 465.725 us; speedup vs baseline: 1.1748x; 1.0772x over previous
//
#include <hip/hip_runtime.h>

// ---------------------------------------------------------------------------
// TextGCN (2-layer GCN, eval mode) on MI355X.
// Fusions:
//   * xw1_word = word @ (W_lin@W1) + (b_lin@W1)  (never materialize [N,768] x)
//   * layer 2: agg(h1@W2)[mask] == agg(h1)[mask] @ W2
// CSR holds RAW weights; symmetric norm applied on the fly (dis[dst] factors
// out of the row sum). Self-loop gets reserved slot offs[i] (no atomic).
// Wide phase dispatches co-schedule independent work:
//   phase1 = fuseGEMM || cnt ; phase2 = fill || docGEMM(split-K 4) || wordGEMM
//   phase3 = degdis || partial-reduce.  Doc partials alias the h1 region.
// GEMM tile body is software-pipelined: register prefetch of the next K-tile
// + LDS double-buffer, single barrier per K-iter (hides ~900cyc load latency
// under the ~1024cyc FMA block).
// ---------------------------------------------------------------------------

// ---- pipelined tiled-SGEMM body: out[R,64] = X[R,K(ldx)] @ W[K,64] (+bias),
// K-range [k0b,k0e); 64x64 tile, BK=32, 256 thr, 4x4 micro-tile.
// LAST: row R-1 is read from lastRow pointer (virtual concat row).
template <bool LAST>
__device__ __forceinline__ void gemm_tile_body(
    const float* __restrict__ X, int ldx, const float* __restrict__ lastRow,
    const float* __restrict__ W, const float* __restrict__ bias,
    float* __restrict__ out, int R, int K, int k0b, int k0e, int row0) {
  __shared__ float Xs[2][32][68];
  __shared__ float Ws[2][32][64];
  const int t = threadIdx.x;
  const int tx = t & 15;
  const int ty = t >> 4;
  const int xr = t >> 3;          // staging: X row within tile (and +32)
  const int xk = (t & 7) << 2;    // staging: X k offset 0,4,...,28
  const int wc = (t & 15) << 2;   // staging: W col 0,4,...,60
  const int wk = t >> 4;          // staging: W k row (and +16)
  float acc[4][4] = {};
  float4 vx[2], vw[2];

  auto load_tiles = [&](int k0) {
#pragma unroll
    for (int h = 0; h < 2; ++h) {
      int gr = row0 + xr + h * 32;
      int gk = k0 + xk;
      vx[h] = make_float4(0.f, 0.f, 0.f, 0.f);
      if (gr < R && gk < K) {
        const float* xp = (LAST && gr == R - 1) ? lastRow : X + (size_t)gr * ldx;
        vx[h] = *(const float4*)(xp + gk);
      }
      int kk = k0 + wk + h * 16;
      vw[h] = make_float4(0.f, 0.f, 0.f, 0.f);
      if (kk < K) vw[h] = *(const float4*)(W + (size_t)kk * 64 + wc);
    }
  };
  auto store_tiles = [&](int buf) {
#pragma unroll
    for (int h = 0; h < 2; ++h) {
      int r = xr + h * 32;
      Xs[buf][xk + 0][r] = vx[h].x;
      Xs[buf][xk + 1][r] = vx[h].y;
      Xs[buf][xk + 2][r] = vx[h].z;
      Xs[buf][xk + 3][r] = vx[h].w;
      *(float4*)&Ws[buf][wk + h * 16][wc] = vw[h];
    }
  };

  const int nIter = (k0e - k0b + 31) / 32;
  load_tiles(k0b);
  store_tiles(0);
  __syncthreads();

  for (int it = 0; it < nIter; ++it) {
    const int buf = it & 1;
    if (it + 1 < nIter) load_tiles(k0b + (it + 1) * 32);   // prefetch next tile
#pragma unroll
    for (int kk = 0; kk < 32; ++kk) {
      float4 xa = *(const float4*)&Xs[buf][kk][ty * 4];
      float4 wb = *(const float4*)&Ws[buf][kk][tx * 4];
      acc[0][0] = fmaf(xa.x, wb.x, acc[0][0]);
      acc[0][1] = fmaf(xa.x, wb.y, acc[0][1]);
      acc[0][2] = fmaf(xa.x, wb.z, acc[0][2]);
      acc[0][3] = fmaf(xa.x, wb.w, acc[0][3]);
      acc[1][0] = fmaf(xa.y, wb.x, acc[1][0]);
      acc[1][1] = fmaf(xa.y, wb.y, acc[1][1]);
      acc[1][2] = fmaf(xa.y, wb.z, acc[1][2]);
      acc[1][3] = fmaf(xa.y, wb.w, acc[1][3]);
      acc[2][0] = fmaf(xa.z, wb.x, acc[2][0]);
      acc[2][1] = fmaf(xa.z, wb.y, acc[2][1]);
      acc[2][2] = fmaf(xa.z, wb.z, acc[2][2]);
      acc[2][3] = fmaf(xa.z, wb.w, acc[2][3]);
      acc[3][0] = fmaf(xa.w, wb.x, acc[3][0]);
      acc[3][1] = fmaf(xa.w, wb.y, acc[3][1]);
      acc[3][2] = fmaf(xa.w, wb.z, acc[3][2]);
      acc[3][3] = fmaf(xa.w, wb.w, acc[3][3]);
    }
    if (it + 1 < nIter) {
      store_tiles(buf ^ 1);   // write other buffer (readers of it synced last iter)
      __syncthreads();
    }
  }

  float b0 = 0.f, b1 = 0.f, b2 = 0.f, b3 = 0.f;
  if (bias) {
    b0 = bias[tx * 4 + 0]; b1 = bias[tx * 4 + 1];
    b2 = bias[tx * 4 + 2]; b3 = bias[tx * 4 + 3];
  }
#pragma unroll
  for (int i = 0; i < 4; ++i) {
    int gr = row0 + ty * 4 + i;
    if (gr < R) {
      float4 o;
      o.x = acc[i][0] + b0;
      o.y = acc[i][1] + b1;
      o.z = acc[i][2] + b2;
      o.w = acc[i][3] + b3;
      *(float4*)(out + (size_t)gr * 64 + tx * 4) = o;
    }
  }
}

// phase1: blocks [0,gemmTiles) fuse GEMM [Wlin;blin]@W1 -> WfuseB[301,64];
//         blocks [gemmTiles,..) cnt histogram over edge destinations.
__global__ __launch_bounds__(256) void k_phase1(
    const float* __restrict__ Wlin, const float* __restrict__ blin,
    const float* __restrict__ W1, float* __restrict__ WfuseB,
    const int* __restrict__ ei, int E, int* __restrict__ cnt, int gemmTiles) {
  int b = blockIdx.x;
  if (b < gemmTiles) {
    gemm_tile_body<true>(Wlin, 768, blin, W1, nullptr, WfuseB, 301, 768, 0, 768, b * 64);
    return;
  }
  int e = (b - gemmTiles) * 256 + threadIdx.x;
  if (e < E) atomicAdd(cnt + ei[E + e], 1);
}

// ---- 3-kernel exclusive scan of (cnt[i]+1) -> offs[N+1]; writes self-loop
// entry at offs[i] and cursor[i]=offs[i]+1 ----
__global__ void k_scan_reduce(const int* __restrict__ cnt, int N, int* __restrict__ bsum) {
  __shared__ int sd[256];
  int b = blockIdx.x, t = threadIdx.x;
  int base = b * 1024 + t * 4;
  int s = 0;
#pragma unroll
  for (int j = 0; j < 4; ++j) s += (base + j < N) ? cnt[base + j] + 1 : 0;
  sd[t] = s; __syncthreads();
  for (int off = 128; off > 0; off >>= 1) {
    if (t < off) sd[t] += sd[t + off];
    __syncthreads();
  }
  if (t == 0) bsum[b] = sd[0];
}

__global__ void k_scan_small(int* __restrict__ bsum, int nb) {
  __shared__ int s[128];
  int t = threadIdx.x;
  int v = (t < nb) ? bsum[t] : 0;
  s[t] = v; __syncthreads();
  for (int off = 1; off < 128; off <<= 1) {
    int x = (t >= off) ? s[t - off] : 0;
    __syncthreads();
    s[t] += x;
    __syncthreads();
  }
  if (t < nb) bsum[t] = s[t] - v;   // exclusive
}

__global__ void k_scan_final(const int* __restrict__ cnt, int N, const int* __restrict__ bsum,
                             int* __restrict__ offs, int* __restrict__ cursor,
                             int2* __restrict__ entries) {
  __shared__ int sd[256];
  int b = blockIdx.x, t = threadIdx.x;
  int base = b * 1024 + t * 4;
  int v[4], loc = 0;
#pragma unroll
  for (int j = 0; j < 4; ++j) { v[j] = (base + j < N) ? cnt[base + j] + 1 : 0; loc += v[j]; }
  sd[t] = loc; __syncthreads();
  for (int off = 1; off < 256; off <<= 1) {
    int x = (t >= off) ? sd[t - off] : 0;
    __syncthreads();
    sd[t] += x;
    __syncthreads();
  }
  int run = bsum[b] + sd[t] - loc;
#pragma unroll
  for (int j = 0; j < 4; ++j) {
    if (base + j < N) {
      int i = base + j;
      offs[i] = run;
      cursor[i] = run + 1;                               // slot 0 = self loop
      entries[run] = make_int2(i, __float_as_int(1.0f)); // raw w=1
      run += v[j];
    }
  }
  if (b == gridDim.x - 1 && t == 255) offs[N] = run;  // total = N + E
}

// phase2: blocks [0,fillBlocks) CSR fill; then doc split-K GEMM tiles; then word GEMM.
__global__ __launch_bounds__(256) void k_phase2(
    const int* __restrict__ ei, const float* __restrict__ ew, int E,
    int* __restrict__ cursor, int2* __restrict__ entries,
    const float* __restrict__ doc, const float* __restrict__ W1,
    float* __restrict__ Pdoc, int ND,
    const float* __restrict__ wordf, const float* __restrict__ WfuseB,
    float* __restrict__ xw1word, int NW,
    int fillBlocks, int docTiles, int nsplit) {
  int b = blockIdx.x;
  if (b < fillBlocks) {
    int e = b * 256 + threadIdx.x;
    if (e < E) {
      int r = ei[e], c = ei[E + e];
      int pos = atomicAdd(cursor + c, 1);
      entries[pos] = make_int2(r, __float_as_int(ew[e]));
    }
    return;
  }
  b -= fillBlocks;
  int docBlocks = docTiles * nsplit;
  if (b < docBlocks) {
    int s = b / docTiles, tile = b % docTiles;
    gemm_tile_body<false>(doc, 768, nullptr, W1, nullptr,
                          Pdoc + (size_t)s * ND * 64, ND, 768,
                          s * 192, s * 192 + 192, tile * 64);
  } else {
    b -= docBlocks;
    gemm_tile_body<false>(wordf, 300, nullptr, WfuseB, WfuseB + (size_t)300 * 64,
                          xw1word, NW, 300, 0, 300, b * 64);
  }
}

// phase3: blocks [0,degBlocks) deg->dis (segmented sum over CSR rows, atomic-free);
//         remaining blocks reduce the 4 doc partials into xw1[0..ND).
__global__ void k_phase3(const int2* __restrict__ entries, const int* __restrict__ offs,
                         float* __restrict__ dis, int N,
                         const float* __restrict__ Pdoc, float* __restrict__ xw1,
                         int ND, int degBlocks) {
  int b = blockIdx.x;
  if (b < degBlocks) {
    int i = b * 256 + threadIdx.x;
    if (i >= N) return;
    int p = offs[i], pe = offs[i + 1];
    float d = 0.f;
    for (; p < pe; ++p) d += __int_as_float(entries[p].y);
    dis[i] = d > 0.f ? rsqrtf(fmaxf(d, 1e-12f)) : 0.f;
    return;
  }
  int i = (b - degBlocks) * 256 + threadIdx.x;   // float4 index
  int n4 = ND * 16;
  if (i >= n4) return;
  const float4* P0 = (const float4*)Pdoc;
  size_t stride = (size_t)ND * 16;
  float4 a = P0[i];
  float4 c1 = P0[i + stride];
  float4 c2 = P0[i + 2 * stride];
  float4 c3 = P0[i + 3 * stride];
  float4 o;
  o.x = a.x + c1.x + c2.x + c3.x;
  o.y = a.y + c1.y + c2.y + c3.y;
  o.z = a.z + c1.z + c2.z + c3.z;
  o.w = a.w + c1.w + c2.w + c3.w;
  ((float4*)xw1)[i] = o;
}

// shared gather-accumulate over one CSR row, 8-wide batches for MLP latency
__device__ __forceinline__ float row_gather(const float* __restrict__ xin,
                                            const int2* __restrict__ entries,
                                            const float* __restrict__ dis,
                                            int p, int pe, int lane) {
  float acc = 0.f;
  for (; p + 8 <= pe; p += 8) {
    int2 e[8];
#pragma unroll
    for (int j = 0; j < 8; ++j) e[j] = entries[p + j];
    float w[8];
#pragma unroll
    for (int j = 0; j < 8; ++j) w[j] = __int_as_float(e[j].y) * dis[e[j].x];
    float x[8];
#pragma unroll
    for (int j = 0; j < 8; ++j) x[j] = xin[(size_t)e[j].x * 64 + lane];
#pragma unroll
    for (int j = 0; j < 8; ++j) acc = fmaf(x[j], w[j], acc);
  }
  for (; p + 4 <= pe; p += 4) {
    int2 e[4];
#pragma unroll
    for (int j = 0; j < 4; ++j) e[j] = entries[p + j];
    float w[4];
#pragma unroll
    for (int j = 0; j < 4; ++j) w[j] = __int_as_float(e[j].y) * dis[e[j].x];
    float x[4];
#pragma unroll
    for (int j = 0; j < 4; ++j) x[j] = xin[(size_t)e[j].x * 64 + lane];
#pragma unroll
    for (int j = 0; j < 4; ++j) acc = fmaf(x[j], w[j], acc);
  }
  for (; p < pe; ++p) {
    int2 e = entries[p];
    acc = fmaf(xin[(size_t)e.x * 64 + lane], __int_as_float(e.y) * dis[e.x], acc);
  }
  return acc;
}

// layer-1 aggregation: out[i] = relu(b1 + dis[i] * sum (w*dis[src]) * x[src])
__global__ void k_agg(const float* __restrict__ xin, const int2* __restrict__ entries,
                      const int* __restrict__ offs, const float* __restrict__ dis,
                      const float* __restrict__ bias, float* __restrict__ xout, int N) {
  const int lane = threadIdx.x & 63;
  const int wv = threadIdx.x >> 6;
  int i = blockIdx.x * 4 + wv;
  if (i >= N) return;
  float acc = row_gather(xin, entries, dis, offs[i], offs[i + 1], lane);
  acc = fmaf(acc, dis[i], bias[lane]);
  acc = fmaxf(acc, 0.f);
  xout[(size_t)i * 64 + lane] = acc;
}

// masked layer-2 aggregation (no bias/relu; GEMM adds b2) + emit y[mask]
__global__ void k_agg2m(const float* __restrict__ xin, const int2* __restrict__ entries,
                        const int* __restrict__ offs, const float* __restrict__ dis,
                        const int* __restrict__ mask, const int* __restrict__ y,
                        float* __restrict__ tout, float* __restrict__ outY, int M) {
  const int lane = threadIdx.x & 63;
  const int wv = threadIdx.x >> 6;
  int o = blockIdx.x * 4 + wv;
  if (o >= M) return;
  int i = mask[o];
  float acc = row_gather(xin, entries, dis, offs[i], offs[i + 1], lane);
  tout[(size_t)o * 64 + lane] = acc * dis[i];
  if (lane == 0) outY[o] = (float)y[i];
}

// plain GEMM wrapper for the final [M,64]@[64,64]+b2
__global__ __launch_bounds__(256) void k_gemm(const float* __restrict__ X, int ldx,
                                              const float* __restrict__ W,
                                              const float* __restrict__ bias,
                                              float* __restrict__ out, int R, int K) {
  gemm_tile_body<false>(X, ldx, nullptr, W, bias, out, R, K, 0, K, blockIdx.x * 64);
}

extern "C" void kernel_launch(void* const* d_in, const int* in_sizes, int n_in,
                              void* d_out, int out_size, void* d_ws, size_t ws_size,
                              hipStream_t stream) {
  const float* doc   = (const float*)d_in[0];
  const float* wordf = (const float*)d_in[1];
  const float* ew    = (const float*)d_in[2];
  const float* Wlin  = (const float*)d_in[3];
  const float* blin  = (const float*)d_in[4];
  const float* W1    = (const float*)d_in[5];
  const float* b1    = (const float*)d_in[6];
  const float* W2    = (const float*)d_in[7];
  const float* b2    = (const float*)d_in[8];
  const int*   ei    = (const int*)d_in[9];
  const int*   mask  = (const int*)d_in[10];
  const int*   y     = (const int*)d_in[11];

  const int E  = in_sizes[2];
  const int M  = in_sizes[10];
  const int ND = in_sizes[0] / 768;
  const int NW = in_sizes[1] / 300;
  const int N  = ND + NW;
  const int NE = N + E;
  const int NSPLIT = 4;

  // workspace carve (aligned 256B)
  char* p = (char*)d_ws;
  auto carve = [&](size_t bytes) -> void* {
    void* q = (void*)p;
    p += (bytes + 255) & ~(size_t)255;
    return q;
  };
  float* WfuseB = (float*)carve(301 * 64 * 4);    // rows 0..299 Wfuse, row 300 bfuse
  float* dis    = (float*)carve((size_t)N * 4);
  int*   cnt    = (int*)carve((size_t)N * 4);
  int*   offs   = (int*)carve(((size_t)N + 1) * 4);
  int*   cursor = (int*)carve((size_t)N * 4);
  int*   bsum   = (int*)carve(1024);
  int2*  entries = (int2*)carve((size_t)NE * 8);
  float* xw1    = (float*)carve((size_t)N * 64 * 4);
  float* h1     = (float*)carve((size_t)N * 64 * 4);  // also holds doc partials
  float* Pdoc   = h1;    // 4*ND*64*4 = 20.5MB <= 25.6MB; dead before k_agg writes h1
  float* tmask  = xw1;   // xw1 dead after k_agg

  hipMemsetAsync(cnt, 0, (size_t)N * 4, stream);

  // phase1: fuse GEMM (5 tiles) || cnt histogram
  const int fuseTiles = (301 + 63) / 64;
  const int cntBlocks = (E + 255) / 256;
  k_phase1<<<fuseTiles + cntBlocks, 256, 0, stream>>>(Wlin, blin, W1, WfuseB, ei, E, cnt, fuseTiles);

  int nb = (N + 1023) / 1024;
  k_scan_reduce<<<nb, 256, 0, stream>>>(cnt, N, bsum);
  k_scan_small<<<1, 128, 0, stream>>>(bsum, nb);
  k_scan_final<<<nb, 256, 0, stream>>>(cnt, N, bsum, offs, cursor, entries);

  // phase2: CSR fill || doc GEMM (split-K 4 -> partials) || word GEMM
  const int fillBlocks = (E + 255) / 256;
  const int docTiles   = (ND + 63) / 64;
  const int wordTiles  = (NW + 63) / 64;
  k_phase2<<<fillBlocks + docTiles * NSPLIT + wordTiles, 256, 0, stream>>>(
      ei, ew, E, cursor, entries,
      doc, W1, Pdoc, ND,
      wordf, WfuseB, xw1 + (size_t)ND * 64, NW,
      fillBlocks, docTiles, NSPLIT);

  // phase3: degdis || partial-reduce into xw1[0..ND)
  const int degBlocks = (N + 255) / 256;
  const int redBlocks = (ND * 16 + 255) / 256;
  k_phase3<<<degBlocks + redBlocks, 256, 0, stream>>>(entries, offs, dis, N,
                                                      Pdoc, xw1, ND, degBlocks);

  // layer-1 aggregation (+b1, relu)
  k_agg<<<(N + 3) / 4, 256, 0, stream>>>(xw1, entries, offs, dis, b1, h1, N);

  // layer-2: masked aggregation over h1, then project [M,64]@[64,64]+b2
  float* out0 = (float*)d_out;
  float* outY = out0 + (size_t)M * 64;
  k_agg2m<<<(M + 3) / 4, 256, 0, stream>>>(h1, entries, offs, dis, mask, y, tmask, outY, M);
  k_gemm<<<(M + 63) / 64, 256, 0, stream>>>(tmask, 64, W2, b2, out0, M, 64);
}

// Round 6
// 435.802 us; speedup vs baseline: 1.2555x; 1.0687x over previous
//
#include <hip/hip_runtime.h>

// ---------------------------------------------------------------------------
// TextGCN (2-layer GCN, eval mode) on MI355X.
// Fusions:
//   * xw1_word = word @ (W_lin@W1) + (b_lin@W1)  (never materialize [N,768] x)
//   * layer 2: agg(h1@W2)[mask] == agg(h1)[mask] @ W2
// CSR holds RAW weights; symmetric norm applied on the fly. Self-loop gets
// reserved slot offs[i] (no atomic).
// All dense projections use bf16 MFMA (16x16x32, fp32 accumulate): wave-per-
// 16-rows, no LDS, no barriers -- latency hidden purely by occupancy.
// Weights pre-packed once into B-fragment order (n=lane&15+16g, k=quad*8+j).
// Phases co-schedule independent work:
//   phase1 = fuseGEMM(strided-B) || packW1 || cnt
//   scanR  = scan_reduce || packWfuse || packW2
//   phase2 = fill || docMFMA || wordMFMA
// ---------------------------------------------------------------------------

typedef __attribute__((ext_vector_type(8))) short short8;   // 8 bf16 = 4 VGPR
typedef __attribute__((ext_vector_type(4))) float float4v;  // MFMA C/D frag

__device__ __forceinline__ unsigned short f2bf(float f) {   // RNE f32->bf16
  unsigned u = __float_as_uint(f);
  return (unsigned short)((u + 0x7FFFu + ((u >> 16) & 1u)) >> 16);
}

// pack W[K,64] fp32 -> bf16 fragment order: pack[((g*nk0+k0)*64+lane)*8+j]
// holds W[k0*32+quad*8+j][ (lane&15)+16g ], zero-padded past K.
// Exactly nk0 blocks of 256 threads (4 groups * 64 lanes per k0).
__device__ __forceinline__ void pack_w_body(const float* __restrict__ W, int K,
                                            int nk0, unsigned short* __restrict__ pack,
                                            int tid) {
  int lane = tid & 63;
  int rest = tid >> 6;
  int k0 = rest % nk0;
  int g = rest / nk0;
  int quad = lane >> 4;
  int n = (lane & 15) + g * 16;
  short8 v;
#pragma unroll
  for (int j = 0; j < 8; ++j) {
    int k = k0 * 32 + quad * 8 + j;
    float w = (k < K) ? W[(size_t)k * 64 + n] : 0.f;
    v[j] = (short)f2bf(w);
  }
  *(short8*)(pack + (((size_t)(g * nk0 + k0) * 64 + lane) << 3)) = v;
}

// MFMA GEMM: out[R,64] = X[R,K(ldx)] @ W[K,64] (+bias). One wave = 16 rows.
// PACKED: B from pre-packed bf16 fragments; else strided fp32 loads from Wf.
// LAST: row R-1 is read from lastRow (virtual concat row).
template <bool LAST, bool PACKED>
__device__ __forceinline__ void mfma_gemm_body(
    const float* __restrict__ X, int ldx, const float* __restrict__ lastRow,
    const unsigned short* __restrict__ Wpack, const float* __restrict__ Wf,
    int nk0, int K, const float* __restrict__ bias,
    float* __restrict__ out, int R, int waveIdx) {
  int r0 = waveIdx * 16;
  if (r0 >= R) return;
  const int lane = threadIdx.x & 63;
  const int quad = lane >> 4;
  const int m = lane & 15;
  const int row = r0 + m;
  const float* xrow = nullptr;
  if (row < R) xrow = (LAST && row == R - 1) ? lastRow : X + (size_t)row * ldx;

  float4v acc[4];
#pragma unroll
  for (int g = 0; g < 4; ++g) acc[g] = (float4v){0.f, 0.f, 0.f, 0.f};

  for (int k0 = 0; k0 < nk0; ++k0) {
    int kb = k0 * 32 + quad * 8;
    float a[8];
    if (xrow && kb + 8 <= K) {
      float4 v0 = *(const float4*)(xrow + kb);
      float4 v1 = *(const float4*)(xrow + kb + 4);
      a[0] = v0.x; a[1] = v0.y; a[2] = v0.z; a[3] = v0.w;
      a[4] = v1.x; a[5] = v1.y; a[6] = v1.z; a[7] = v1.w;
    } else {
#pragma unroll
      for (int j = 0; j < 8; ++j) {
        int k = kb + j;
        a[j] = (xrow && k < K) ? xrow[k] : 0.f;
      }
    }
    short8 af;
#pragma unroll
    for (int j = 0; j < 8; ++j) af[j] = (short)f2bf(a[j]);
#pragma unroll
    for (int g = 0; g < 4; ++g) {
      short8 bf;
      if (PACKED) {
        bf = *(const short8*)(Wpack + (((size_t)(g * nk0 + k0) * 64 + lane) << 3));
      } else {
        int n = g * 16 + m;
#pragma unroll
        for (int j = 0; j < 8; ++j) {
          int k = kb + j;
          float w = (k < K) ? Wf[(size_t)k * 64 + n] : 0.f;
          bf[j] = (short)f2bf(w);
        }
      }
      acc[g] = __builtin_amdgcn_mfma_f32_16x16x32_bf16(af, bf, acc[g], 0, 0, 0);
    }
  }

#pragma unroll
  for (int g = 0; g < 4; ++g) {
    float b = bias ? bias[g * 16 + m] : 0.f;
#pragma unroll
    for (int reg = 0; reg < 4; ++reg) {
      int r = r0 + quad * 4 + reg;    // C/D: col=lane&15, row=quad*4+reg
      if (r < R) out[(size_t)r * 64 + g * 16 + m] = acc[g][reg] + b;
    }
  }
}

// phase1: [fuseBlocks) fuse GEMM [Wlin;blin]@W1 -> WfuseB[301,64] (strided B);
//         [+packBlocks) pack W1 -> packW1; rest: cnt histogram.
__global__ __launch_bounds__(256) void k_phase1(
    const float* __restrict__ Wlin, const float* __restrict__ blin,
    const float* __restrict__ W1, float* __restrict__ WfuseB,
    unsigned short* __restrict__ packW1,
    const int* __restrict__ ei, int E, int* __restrict__ cnt,
    int fuseBlocks, int packBlocks) {
  int b = blockIdx.x;
  if (b < fuseBlocks) {
    mfma_gemm_body<true, false>(Wlin, 768, blin, nullptr, W1, 24, 768,
                                nullptr, WfuseB, 301, b * 4 + (threadIdx.x >> 6));
    return;
  }
  b -= fuseBlocks;
  if (b < packBlocks) {
    pack_w_body(W1, 768, 24, packW1, b * 256 + threadIdx.x);
    return;
  }
  b -= packBlocks;
  int e = b * 256 + threadIdx.x;
  if (e < E) atomicAdd(cnt + ei[E + e], 1);
}

// ---- scan of (cnt[i]+1) -> offs[N+1]; also packs Wfuse & W2 in reduce pass ----
__global__ void k_scan_reduce(const int* __restrict__ cnt, int N, int* __restrict__ bsum,
                              const float* __restrict__ WfuseB, unsigned short* __restrict__ packWf,
                              const float* __restrict__ W2, unsigned short* __restrict__ packW2,
                              int nb) {
  int b = blockIdx.x, t = threadIdx.x;
  if (b >= nb) {
    b -= nb;
    if (b < 10) pack_w_body(WfuseB, 300, 10, packWf, b * 256 + t);
    else pack_w_body(W2, 64, 2, packW2, (b - 10) * 256 + t);
    return;
  }
  __shared__ int sd[256];
  int base = b * 1024 + t * 4;
  int s = 0;
#pragma unroll
  for (int j = 0; j < 4; ++j) s += (base + j < N) ? cnt[base + j] + 1 : 0;
  sd[t] = s; __syncthreads();
  for (int off = 128; off > 0; off >>= 1) {
    if (t < off) sd[t] += sd[t + off];
    __syncthreads();
  }
  if (t == 0) bsum[b] = sd[0];
}

__global__ void k_scan_small(int* __restrict__ bsum, int nb) {
  __shared__ int s[128];
  int t = threadIdx.x;
  int v = (t < nb) ? bsum[t] : 0;
  s[t] = v; __syncthreads();
  for (int off = 1; off < 128; off <<= 1) {
    int x = (t >= off) ? s[t - off] : 0;
    __syncthreads();
    s[t] += x;
    __syncthreads();
  }
  if (t < nb) bsum[t] = s[t] - v;   // exclusive
}

__global__ void k_scan_final(const int* __restrict__ cnt, int N, const int* __restrict__ bsum,
                             int* __restrict__ offs, int* __restrict__ cursor,
                             int2* __restrict__ entries) {
  __shared__ int sd[256];
  int b = blockIdx.x, t = threadIdx.x;
  int base = b * 1024 + t * 4;
  int v[4], loc = 0;
#pragma unroll
  for (int j = 0; j < 4; ++j) { v[j] = (base + j < N) ? cnt[base + j] + 1 : 0; loc += v[j]; }
  sd[t] = loc; __syncthreads();
  for (int off = 1; off < 256; off <<= 1) {
    int x = (t >= off) ? sd[t - off] : 0;
    __syncthreads();
    sd[t] += x;
    __syncthreads();
  }
  int run = bsum[b] + sd[t] - loc;
#pragma unroll
  for (int j = 0; j < 4; ++j) {
    if (base + j < N) {
      int i = base + j;
      offs[i] = run;
      cursor[i] = run + 1;                               // slot 0 = self loop
      entries[run] = make_int2(i, __float_as_int(1.0f)); // raw w=1
      run += v[j];
    }
  }
  if (b == gridDim.x - 1 && t == 255) offs[N] = run;  // total = N + E
}

// phase2: [fillBlocks) CSR fill; [+docBlocks) doc MFMA; rest word MFMA.
__global__ __launch_bounds__(256) void k_phase2(
    const int* __restrict__ ei, const float* __restrict__ ew, int E,
    int* __restrict__ cursor, int2* __restrict__ entries,
    const float* __restrict__ doc, const unsigned short* __restrict__ packW1,
    float* __restrict__ xw1, int ND,
    const float* __restrict__ wordf, const unsigned short* __restrict__ packWf,
    const float* __restrict__ bfuse, float* __restrict__ xw1word, int NW,
    int fillBlocks, int docBlocks) {
  int b = blockIdx.x;
  if (b < fillBlocks) {
    int e = b * 256 + threadIdx.x;
    if (e < E) {
      int r = ei[e], c = ei[E + e];
      int pos = atomicAdd(cursor + c, 1);
      entries[pos] = make_int2(r, __float_as_int(ew[e]));
    }
    return;
  }
  b -= fillBlocks;
  if (b < docBlocks) {
    mfma_gemm_body<false, true>(doc, 768, nullptr, packW1, nullptr, 24, 768,
                                nullptr, xw1, ND, b * 4 + (threadIdx.x >> 6));
  } else {
    b -= docBlocks;
    mfma_gemm_body<false, true>(wordf, 300, nullptr, packWf, nullptr, 10, 300,
                                bfuse, xw1word, NW, b * 4 + (threadIdx.x >> 6));
  }
}

// deg->dis: segmented sum of raw weights over CSR rows (atomic-free)
__global__ void k_degdis(const int2* __restrict__ entries, const int* __restrict__ offs,
                         float* __restrict__ dis, int N) {
  int i = blockIdx.x * blockDim.x + threadIdx.x;
  if (i >= N) return;
  int p = offs[i], pe = offs[i + 1];
  float d = 0.f;
  for (; p < pe; ++p) d += __int_as_float(entries[p].y);
  dis[i] = d > 0.f ? rsqrtf(fmaxf(d, 1e-12f)) : 0.f;
}

// shared gather-accumulate over one CSR row, 8-wide batches for MLP latency
__device__ __forceinline__ float row_gather(const float* __restrict__ xin,
                                            const int2* __restrict__ entries,
                                            const float* __restrict__ dis,
                                            int p, int pe, int lane) {
  float acc = 0.f;
  for (; p + 8 <= pe; p += 8) {
    int2 e[8];
#pragma unroll
    for (int j = 0; j < 8; ++j) e[j] = entries[p + j];
    float w[8];
#pragma unroll
    for (int j = 0; j < 8; ++j) w[j] = __int_as_float(e[j].y) * dis[e[j].x];
    float x[8];
#pragma unroll
    for (int j = 0; j < 8; ++j) x[j] = xin[(size_t)e[j].x * 64 + lane];
#pragma unroll
    for (int j = 0; j < 8; ++j) acc = fmaf(x[j], w[j], acc);
  }
  for (; p + 4 <= pe; p += 4) {
    int2 e[4];
#pragma unroll
    for (int j = 0; j < 4; ++j) e[j] = entries[p + j];
    float w[4];
#pragma unroll
    for (int j = 0; j < 4; ++j) w[j] = __int_as_float(e[j].y) * dis[e[j].x];
    float x[4];
#pragma unroll
    for (int j = 0; j < 4; ++j) x[j] = xin[(size_t)e[j].x * 64 + lane];
#pragma unroll
    for (int j = 0; j < 4; ++j) acc = fmaf(x[j], w[j], acc);
  }
  for (; p < pe; ++p) {
    int2 e = entries[p];
    acc = fmaf(xin[(size_t)e.x * 64 + lane], __int_as_float(e.y) * dis[e.x], acc);
  }
  return acc;
}

// layer-1 aggregation: out[i] = relu(b1 + dis[i] * sum (w*dis[src]) * x[src])
__global__ void k_agg(const float* __restrict__ xin, const int2* __restrict__ entries,
                      const int* __restrict__ offs, const float* __restrict__ dis,
                      const float* __restrict__ bias, float* __restrict__ xout, int N) {
  const int lane = threadIdx.x & 63;
  const int wv = threadIdx.x >> 6;
  int i = blockIdx.x * 4 + wv;
  if (i >= N) return;
  float acc = row_gather(xin, entries, dis, offs[i], offs[i + 1], lane);
  acc = fmaf(acc, dis[i], bias[lane]);
  acc = fmaxf(acc, 0.f);
  xout[(size_t)i * 64 + lane] = acc;
}

// masked layer-2 aggregation (no bias/relu; final GEMM adds b2) + emit y[mask]
__global__ void k_agg2m(const float* __restrict__ xin, const int2* __restrict__ entries,
                        const int* __restrict__ offs, const float* __restrict__ dis,
                        const int* __restrict__ mask, const int* __restrict__ y,
                        float* __restrict__ tout, float* __restrict__ outY, int M) {
  const int lane = threadIdx.x & 63;
  const int wv = threadIdx.x >> 6;
  int o = blockIdx.x * 4 + wv;
  if (o >= M) return;
  int i = mask[o];
  float acc = row_gather(xin, entries, dis, offs[i], offs[i + 1], lane);
  tout[(size_t)o * 64 + lane] = acc * dis[i];
  if (lane == 0) outY[o] = (float)y[i];
}

// final projection [M,64]@[64,64]+b2 via MFMA (packed W2)
__global__ __launch_bounds__(256) void k_mfma_final(
    const float* __restrict__ X, const unsigned short* __restrict__ packW2,
    const float* __restrict__ b2, float* __restrict__ out, int M) {
  mfma_gemm_body<false, true>(X, 64, nullptr, packW2, nullptr, 2, 64,
                              b2, out, M, blockIdx.x * 4 + (threadIdx.x >> 6));
}

extern "C" void kernel_launch(void* const* d_in, const int* in_sizes, int n_in,
                              void* d_out, int out_size, void* d_ws, size_t ws_size,
                              hipStream_t stream) {
  const float* doc   = (const float*)d_in[0];
  const float* wordf = (const float*)d_in[1];
  const float* ew    = (const float*)d_in[2];
  const float* Wlin  = (const float*)d_in[3];
  const float* blin  = (const float*)d_in[4];
  const float* W1    = (const float*)d_in[5];
  const float* b1    = (const float*)d_in[6];
  const float* W2    = (const float*)d_in[7];
  const float* b2    = (const float*)d_in[8];
  const int*   ei    = (const int*)d_in[9];
  const int*   mask  = (const int*)d_in[10];
  const int*   y     = (const int*)d_in[11];

  const int E  = in_sizes[2];
  const int M  = in_sizes[10];
  const int ND = in_sizes[0] / 768;
  const int NW = in_sizes[1] / 300;
  const int N  = ND + NW;
  const int NE = N + E;

  // workspace carve (aligned 256B)
  char* p = (char*)d_ws;
  auto carve = [&](size_t bytes) -> void* {
    void* q = (void*)p;
    p += (bytes + 255) & ~(size_t)255;
    return q;
  };
  float*          WfuseB = (float*)carve(301 * 64 * 4);  // rows 0..299 Wfuse, row 300 bfuse
  unsigned short* packW1 = (unsigned short*)carve((size_t)4 * 24 * 64 * 8 * 2);
  unsigned short* packWf = (unsigned short*)carve((size_t)4 * 10 * 64 * 8 * 2);
  unsigned short* packW2 = (unsigned short*)carve((size_t)4 * 2 * 64 * 8 * 2);
  float* dis    = (float*)carve((size_t)N * 4);
  int*   cnt    = (int*)carve((size_t)N * 4);
  int*   offs   = (int*)carve(((size_t)N + 1) * 4);
  int*   cursor = (int*)carve((size_t)N * 4);
  int*   bsum   = (int*)carve(1024);
  int2*  entries = (int2*)carve((size_t)NE * 8);
  float* xw1    = (float*)carve((size_t)N * 64 * 4);
  float* h1     = (float*)carve((size_t)N * 64 * 4);
  float* tmask  = xw1;   // xw1 dead after k_agg

  hipMemsetAsync(cnt, 0, (size_t)N * 4, stream);

  // phase1: fuse MFMA (strided B) || pack W1 || cnt histogram
  const int fuseBlocks = (301 + 63) / 64;    // 5 blocks * 4 waves >= 19 waves
  const int packBlocks = 24;                 // 4*24*64 threads exactly
  const int cntBlocks  = (E + 255) / 256;
  k_phase1<<<fuseBlocks + packBlocks + cntBlocks, 256, 0, stream>>>(
      Wlin, blin, W1, WfuseB, packW1, ei, E, cnt, fuseBlocks, packBlocks);

  int nb = (N + 1023) / 1024;
  k_scan_reduce<<<nb + 12, 256, 0, stream>>>(cnt, N, bsum, WfuseB, packWf, W2, packW2, nb);
  k_scan_small<<<1, 128, 0, stream>>>(bsum, nb);
  k_scan_final<<<nb, 256, 0, stream>>>(cnt, N, bsum, offs, cursor, entries);

  // phase2: CSR fill || doc MFMA || word MFMA
  const int fillBlocks = (E + 255) / 256;
  const int docBlocks  = (ND + 63) / 64;     // 4 waves/block * 16 rows/wave
  const int wordBlocks = (NW + 63) / 64;
  k_phase2<<<fillBlocks + docBlocks + wordBlocks, 256, 0, stream>>>(
      ei, ew, E, cursor, entries,
      doc, packW1, xw1, ND,
      wordf, packWf, WfuseB + (size_t)300 * 64, xw1 + (size_t)ND * 64, NW,
      fillBlocks, docBlocks);

  k_degdis<<<(N + 255) / 256, 256, 0, stream>>>(entries, offs, dis, N);

  // layer-1 aggregation (+b1, relu)
  k_agg<<<(N + 3) / 4, 256, 0, stream>>>(xw1, entries, offs, dis, b1, h1, N);

  // layer-2: masked aggregation over h1, then project [M,64]@[64,64]+b2
  float* out0 = (float*)d_out;
  float* outY = out0 + (size_t)M * 64;
  k_agg2m<<<(M + 3) / 4, 256, 0, stream>>>(h1, entries, offs, dis, mask, y, tmask, outY, M);
  k_mfma_final<<<(M + 63) / 64, 256, 0, stream>>>(tmask, packW2, b2, out0, M);
}